// Round 12
// baseline (759.368 us; speedup 1.0000x reference)
//
#include <hip/hip_runtime.h>

// ---------------------------------------------------------------------------
// ConvLSTMNet round 19:
//  - lstm: exact R17 (303 us: prescale fold, product-major MFMA, xv prefetch,
//    unroll-2, fc-bias prefill folded in as 10 extra blocks).
//  - FC: transposed-lane fc_gemm. Diagnosis: R10's fc2 was LDS-issue-bound
//    (6.2M ds_read_b128 total: 4 per k feeding 16 FMAs). New scheme:
//    lane = m-row, wave = 16 n-cols. Per k: ONE conflict-free ds_read_b32
//    (A, pad-65 layout) + W[k][n0..n0+16] wave-uniform -> s_load_dwordx4/x16
//    on the scalar pipe (readfirstlane-forced SGPR base) + 16 VALU FMA.
//    LDS pressure ~5x down; W leaves the vector-memory path. Epilogue
//    transposes acc through the reused LDS buffer -> coalesced atomics.
//    Same grids/kchunks/atomics as R10; k-ascending order -> same absmax.
// ---------------------------------------------------------------------------

#define T_STEPS 256
#define PIX 55
#define MT 16          // sequences per tile (MFMA N-dim)
#define TILES 110      // 1760 / 16
#define LSTM_BLOCKS 440
#define INIT_BLOCKS 10
#define LOG2E 1.4426950408889634f

typedef float f32x4 __attribute__((ext_vector_type(4)));
typedef __bf16 bf16x8 __attribute__((ext_vector_type(8)));
typedef __bf16 bf16x4 __attribute__((ext_vector_type(4)));

__global__ __launch_bounds__(256) void lstm_kernel(
    const float* __restrict__ x1, const float* __restrict__ x2,
    const float* __restrict__ wx1, const float* __restrict__ wh1,
    const float* __restrict__ bx1, const float* __restrict__ bh1,
    const float* __restrict__ wx2, const float* __restrict__ wh2,
    const float* __restrict__ bx2, const float* __restrict__ bh2,
    float* __restrict__ feat,   // [64][7040]: row sub*32+b, col (cell*64+u)*55+p
    const float* __restrict__ fb2, const float* __restrict__ fb3,
    const float* __restrict__ fb4, const float* __restrict__ fb5,
    float* __restrict__ t1, float* __restrict__ t2,
    float* __restrict__ t3, float* __restrict__ o)
{
    int bid  = blockIdx.x;            // 0..449
    int tid  = threadIdx.x;

    if (bid >= LSTM_BLOCKS) {
        // ---- bias prefill for the FC outputs (runs under the lstm) ----
        int base = (bid - LSTM_BLOCKS) * 256 + tid;      // 0..2559
        const int n1 = 64 * 3400, n2 = 64 * 1000, n3 = 64 * 500, n4 = 64 * 50;
        const int tot = n1 + n2 + n3 + n4;               // 316800
        for (int i = base; i < tot; i += 256 * INIT_BLOCKS) {
            int j = i;
            if (j < n1) { t1[j] = fb2[j % 3400]; continue; }
            j -= n1;
            if (j < n2) { t2[j] = fb3[j % 1000]; continue; }
            j -= n2;
            if (j < n3) { t3[j] = fb4[j % 500]; continue; }
            o[j - n3] = fb5[(j - n3) % 50];
        }
        return;
    }

    int tile = bid % TILES;
    int cc   = bid / TILES;           // 0..3
    int sub  = cc >> 1, cell = cc & 1;
    const float* x  = sub  ? x2  : x1;
    const float* wx = cell ? wx2 : wx1;
    const float* wh = cell ? wh2 : wh1;
    const float* bx = cell ? bx2 : bx1;
    const float* bh = cell ? bh2 : bh1;

    int w    = tid >> 6;              // wave id = unit subtile (units 16w..16w+15)
    int l    = tid & 63;
    int quad = l >> 4;
    int c16  = l & 15;

    __shared__ float xl[MT * 514];                        // [seq][t*2+c], pad 514
    __shared__ __align__(16) __bf16 hb[2][2][MT][72];     // [buf][hi/lo][seq][u pad72]

    // ---- stage x for this block's 16 sequences (all 256 steps) ----
    {
        int seq0 = tile * MT;
        for (int i = 0; i < 32; ++i) {
            int idx = tid + 256 * i;          // m*512 + t*2 + c
            int m = idx >> 9;
            int tc = idx & 511;
            int t = tc >> 1, c = tc & 1;
            int seq = seq0 + m;
            int b = seq / PIX, p = seq % PIX;
            xl[m * 514 + tc] = x[((b * T_STEPS + t) * 2 + c) * PIX + p];
        }
    }
    // ---- zero h buffers ----
    {
        __bf16* hz = &hb[0][0][0][0];
        for (int i = tid; i < 2 * 2 * MT * 72; i += 256) hz[i] = (__bf16)0.0f;
    }

    // ---- W as A-operand fragments (hi+lo), per gate & K-slab, PRESCALED ----
    bf16x8 Whi[4][2], Wlo[4][2];
    float btot[4][4], wxa[4][4], wxb[4][4];
#pragma unroll
    for (int g = 0; g < 4; ++g) {
        float sg = (g == 3) ? (-2.0f * LOG2E) : (-LOG2E);
        int col = 64 * g + 16 * w + c16;
#pragma unroll
        for (int r = 0; r < 4; ++r) {
            int u = 64 * g + 16 * w + 4 * quad + r;   // this thread's C-row units
            btot[g][r] = sg * (bx[u] + bh[u]);
            wxa[g][r]  = sg * wx[u];
            wxb[g][r]  = sg * wx[256 + u];
        }
#pragma unroll
        for (int q = 0; q < 2; ++q) {
#pragma unroll
            for (int j = 0; j < 8; ++j) {
                int k = 32 * q + 8 * quad + j;
                float wv = sg * wh[k * 256 + col];
                __bf16 hi = (__bf16)wv;
                Whi[g][q][j] = hi;
                Wlo[g][q][j] = (__bf16)(wv - (float)hi);
            }
        }
    }

    float cst[4]  = {0.f, 0.f, 0.f, 0.f};
    float hfin[4] = {0.f, 0.f, 0.f, 0.f};

    __syncthreads();
    float2 xv = *(const float2*)&xl[c16 * 514 + (cell ? (T_STEPS - 1) : 0) * 2];

#pragma unroll 2
    for (int t = 0; t < T_STEPS; ++t) {
        int rb = t & 1, wb = rb ^ 1;

        bf16x8 Bh[2], Bl[2];
#pragma unroll
        for (int q = 0; q < 2; ++q) {
            Bh[q] = *(const bf16x8*)&hb[rb][0][c16][32 * q + 8 * quad];
            Bl[q] = *(const bf16x8*)&hb[rb][1][c16][32 * q + 8 * quad];
        }

        f32x4 acc[4];
#pragma unroll
        for (int g = 0; g < 4; ++g) {
#pragma unroll
            for (int r = 0; r < 4; ++r)
                acc[g][r] = fmaf(xv.y, wxb[g][r], fmaf(xv.x, wxa[g][r], btot[g][r]));
        }
        // product-major: 6 rounds x 4 gates -> 4-way dependent-chain ILP.
#pragma unroll
        for (int g = 0; g < 4; ++g)
            acc[g] = __builtin_amdgcn_mfma_f32_16x16x32_bf16(Whi[g][0], Bh[0], acc[g], 0, 0, 0);
#pragma unroll
        for (int g = 0; g < 4; ++g)
            acc[g] = __builtin_amdgcn_mfma_f32_16x16x32_bf16(Whi[g][1], Bh[1], acc[g], 0, 0, 0);
#pragma unroll
        for (int g = 0; g < 4; ++g)
            acc[g] = __builtin_amdgcn_mfma_f32_16x16x32_bf16(Wlo[g][0], Bh[0], acc[g], 0, 0, 0);
#pragma unroll
        for (int g = 0; g < 4; ++g)
            acc[g] = __builtin_amdgcn_mfma_f32_16x16x32_bf16(Wlo[g][1], Bh[1], acc[g], 0, 0, 0);
#pragma unroll
        for (int g = 0; g < 4; ++g)
            acc[g] = __builtin_amdgcn_mfma_f32_16x16x32_bf16(Whi[g][0], Bl[0], acc[g], 0, 0, 0);
#pragma unroll
        for (int g = 0; g < 4; ++g)
            acc[g] = __builtin_amdgcn_mfma_f32_16x16x32_bf16(Whi[g][1], Bl[1], acc[g], 0, 0, 0);

        // exp phase: 16 independent transcendentals (acc IS the exp2 arg)
        float ei[4], ef[4], eo[4], eg[4];
#pragma unroll
        for (int r = 0; r < 4; ++r) {
            ei[r] = __builtin_amdgcn_exp2f(acc[0][r]);
            ef[r] = __builtin_amdgcn_exp2f(acc[1][r]);
            eo[r] = __builtin_amdgcn_exp2f(acc[2][r]);
            eg[r] = __builtin_amdgcn_exp2f(acc[3][r]);
        }

        bf16x4 ph, pl;
#pragma unroll
        for (int r = 0; r < 4; ++r) {
            float sf  = __builtin_amdgcn_rcpf(1.0f + ef[r]);
            float itg = (1.0f - eg[r]) * __builtin_amdgcn_rcpf((1.0f + ei[r]) * (1.0f + eg[r]));
            float c   = fmaf(sf, cst[r], itg);
            cst[r] = c;
            float ec = __builtin_amdgcn_exp2f(-2.0f * LOG2E * c);
            float h  = (1.0f - ec) * __builtin_amdgcn_rcpf((1.0f + eo[r]) * (1.0f + ec));
            hfin[r] = h;
            __bf16 hi = (__bf16)h;
            ph[r] = hi;
            pl[r] = (__bf16)(h - (float)hi);
        }
        *(bf16x4*)&hb[wb][0][c16][16 * w + 4 * quad] = ph;
        *(bf16x4*)&hb[wb][1][c16][16 * w + 4 * quad] = pl;

        {
            int txn = (cell ? (T_STEPS - 2 - t) : (t + 1)) & 255;
            xv = *(const float2*)&xl[c16 * 514 + txn * 2];
        }
        __syncthreads();
    }

    {
        int seq = tile * MT + c16;
        int b = seq / PIX, p = seq % PIX;
#pragma unroll
        for (int r = 0; r < 4; ++r) {
            int u = 16 * w + 4 * quad + r;
            feat[(size_t)(sub * 32 + b) * 7040 + (cell * 64 + u) * PIX + p] = hfin[r];
        }
    }
}

// ---------------------------------------------------------------------------
// FC v8 (transposed lanes, scalar W): out[64][N] += A[64][kchunk] @ W.
// Block = 64 m x 64 n, 4 waves; LANE = m-row, WAVE = 16 n-cols (uniform n0
// via readfirstlane). Per k: 1 conflict-free ds_read_b32 of A (pad-65) +
// 16 s_load'd W scalars + 16 VALU FMA. Epilogue: transpose acc through the
// reused LDS buffer -> coalesced atomics into bias-pre-filled out.
// ---------------------------------------------------------------------------
__global__ __launch_bounds__(256) void fc_gemm(const float* __restrict__ A,
                                               const float* __restrict__ W,
                                               float* __restrict__ out,
                                               int K, int N, int kchunk) {
    __shared__ float al[64 * 65];          // [kc][m] pad65; reused as [m][nc] pad65
    int tid = threadIdx.x;
    int l   = tid & 63;                    // compute: m-row. store: n-col.
    int wvu = __builtin_amdgcn_readfirstlane(tid >> 6);   // wave id (SGPR)

    int k0   = blockIdx.y * kchunk;
    int kend = min(K, k0 + kchunk);
    int n0b  = blockIdx.x * 64;
    int n0   = n0b + 16 * wvu;             // wave's n-slice base (uniform)
    bool full = (n0 + 16 <= N);

    float acc[16];
#pragma unroll
    for (int j = 0; j < 16; ++j) acc[j] = 0.0f;

    for (int ks = k0; ks < kend; ks += 64) {
        int kcur = min(64, kend - ks);
        __syncthreads();                   // protect al reuse
        // ---- stage A[0:64][ks:ks+kcur] -> al[kc][m] (coalesced global) ----
#pragma unroll
        for (int i = 0; i < 16; ++i) {
            int idx = tid + 256 * i;       // kc = idx&63, m = idx>>6
            int m = idx >> 6, kc = idx & 63;
            if (kc < kcur) al[kc * 65 + m] = A[(size_t)m * K + ks + kc];
        }
        __syncthreads();

        const float* wr = W + (size_t)ks * N + n0;       // uniform base
        if (full) {
            if (kcur == 64) {
#pragma unroll
                for (int kc = 0; kc < 64; ++kc) {
                    float a = al[kc * 65 + l];
#pragma unroll
                    for (int j = 0; j < 16; ++j)
                        acc[j] = fmaf(a, wr[(size_t)kc * N + j], acc[j]);
                }
            } else {
                for (int kc = 0; kc < kcur; ++kc) {
                    float a = al[kc * 65 + l];
#pragma unroll
                    for (int j = 0; j < 16; ++j)
                        acc[j] = fmaf(a, wr[(size_t)kc * N + j], acc[j]);
                }
            }
        } else {
            for (int kc = 0; kc < kcur; ++kc) {
                float a = al[kc * 65 + l];
#pragma unroll
                for (int j = 0; j < 16; ++j)
                    if (n0 + j < N)
                        acc[j] = fmaf(a, wr[(size_t)kc * N + j], acc[j]);
            }
        }
    }

    // ---- transpose through LDS -> coalesced atomics ----
    __syncthreads();                       // last al reads done
#pragma unroll
    for (int j = 0; j < 16; ++j)
        al[l * 65 + 16 * wvu + j] = acc[j];   // [m][nc], 2-way-free banks
    __syncthreads();
    {
        int nc = l;
        int n  = n0b + nc;
        if (n < N) {
#pragma unroll
            for (int i = 0; i < 16; ++i) {
                int m = 16 * wvu + i;
                unsafeAtomicAdd(&out[(size_t)m * N + n], al[m * 65 + nc]);
            }
        }
    }
}

extern "C" void kernel_launch(void* const* d_in, const int* in_sizes, int n_in,
                              void* d_out, int out_size, void* d_ws, size_t ws_size,
                              hipStream_t stream) {
    const float* x1  = (const float*)d_in[0];
    const float* x2  = (const float*)d_in[1];
    const float* wx1 = (const float*)d_in[2];
    const float* wh1 = (const float*)d_in[3];
    const float* bx1 = (const float*)d_in[4];
    const float* bh1 = (const float*)d_in[5];
    const float* wx2 = (const float*)d_in[6];
    const float* wh2 = (const float*)d_in[7];
    const float* bx2 = (const float*)d_in[8];
    const float* bh2 = (const float*)d_in[9];
    const float* fw2 = (const float*)d_in[10];
    const float* fb2 = (const float*)d_in[11];
    const float* fw3 = (const float*)d_in[12];
    const float* fb3 = (const float*)d_in[13];
    const float* fw4 = (const float*)d_in[14];
    const float* fb4 = (const float*)d_in[15];
    const float* fw5 = (const float*)d_in[16];
    const float* fb5 = (const float*)d_in[17];

    char* ws = (char*)d_ws;
    float* feat = (float*)ws;                                   // [64][7040]
    float* t1   = feat + (size_t)64 * 7040;                     // [64][3400]
    float* t2   = t1   + (size_t)64 * 3400;                     // [64][1000]
    float* t3   = t2   + (size_t)64 * 1000;                     // [64][500]
    float* o    = (float*)d_out;                                // [64][50]

    // lstm (440 blocks) + bias prefill (10 blocks) in one launch
    lstm_kernel<<<dim3(LSTM_BLOCKS + INIT_BLOCKS), dim3(256), 0, stream>>>(
        x1, x2, wx1, wh1, bx1, bh1, wx2, wh2, bx2, bh2, feat,
        fb2, fb3, fb4, fb5, t1, t2, t3, o);

    // atomic split-K GEMMs (out pre-filled with bias)
    fc_gemm<<<dim3(54, 28), dim3(256), 0, stream>>>(feat, fw2, t1, 7040, 3400, 256);
    fc_gemm<<<dim3(16, 54), dim3(256), 0, stream>>>(t1, fw3, t2, 3400, 1000, 64);
    fc_gemm<<<dim3(8, 16), dim3(256), 0, stream>>>(t2, fw4, t3, 1000, 500, 64);
    fc_gemm<<<dim3(1, 16), dim3(256), 0, stream>>>(t3, fw5, o, 500, 50, 32);
}

// Round 13
// 530.017 us; speedup vs baseline: 1.4327x; 1.4327x over previous
//
#include <hip/hip_runtime.h>

// ---------------------------------------------------------------------------
// ConvLSTMNet round 20 (= R17 best-known + fc2 grid repack):
//  - lstm: exact R17 (303 us: prescale fold, product-major MFMA, xv prefetch,
//    unroll-2, fc-bias prefill folded in as 10 extra blocks).
//  - FC: R10 inner loop (proven). fc2 repacked (54 x 19, kchunk 384):
//    machine fill is ~1024 co-resident blocks (4/CU LDS cap); R10's 1512
//    blocks ran 1 full round + a 48%-fill tail round (~35% overhead on the
//    LDS-pipe-bound ~80us kernel). 19x384 covers 7040 with last split = 128
//    exactly -> every stage takes the full-128 hot path; atomics/output
//    28 -> 19. fc3/fc4/fc5 unchanged.
// ---------------------------------------------------------------------------

#define T_STEPS 256
#define PIX 55
#define MT 16          // sequences per tile (MFMA N-dim)
#define TILES 110      // 1760 / 16
#define LSTM_BLOCKS 440
#define INIT_BLOCKS 10
#define LOG2E 1.4426950408889634f
#define FC_SUB 128     // kc per LDS stage
#define FC_GRP 16      // W pipeline depth

typedef float f32x4 __attribute__((ext_vector_type(4)));
typedef __bf16 bf16x8 __attribute__((ext_vector_type(8)));
typedef __bf16 bf16x4 __attribute__((ext_vector_type(4)));

__global__ __launch_bounds__(256) void lstm_kernel(
    const float* __restrict__ x1, const float* __restrict__ x2,
    const float* __restrict__ wx1, const float* __restrict__ wh1,
    const float* __restrict__ bx1, const float* __restrict__ bh1,
    const float* __restrict__ wx2, const float* __restrict__ wh2,
    const float* __restrict__ bx2, const float* __restrict__ bh2,
    float* __restrict__ feat,   // [64][7040]: row sub*32+b, col (cell*64+u)*55+p
    const float* __restrict__ fb2, const float* __restrict__ fb3,
    const float* __restrict__ fb4, const float* __restrict__ fb5,
    float* __restrict__ t1, float* __restrict__ t2,
    float* __restrict__ t3, float* __restrict__ o)
{
    int bid  = blockIdx.x;            // 0..449
    int tid  = threadIdx.x;

    if (bid >= LSTM_BLOCKS) {
        // ---- bias prefill for the FC outputs (runs under the lstm) ----
        int base = (bid - LSTM_BLOCKS) * 256 + tid;      // 0..2559
        const int n1 = 64 * 3400, n2 = 64 * 1000, n3 = 64 * 500, n4 = 64 * 50;
        const int tot = n1 + n2 + n3 + n4;               // 316800
        for (int i = base; i < tot; i += 256 * INIT_BLOCKS) {
            int j = i;
            if (j < n1) { t1[j] = fb2[j % 3400]; continue; }
            j -= n1;
            if (j < n2) { t2[j] = fb3[j % 1000]; continue; }
            j -= n2;
            if (j < n3) { t3[j] = fb4[j % 500]; continue; }
            o[j - n3] = fb5[(j - n3) % 50];
        }
        return;
    }

    int tile = bid % TILES;
    int cc   = bid / TILES;           // 0..3
    int sub  = cc >> 1, cell = cc & 1;
    const float* x  = sub  ? x2  : x1;
    const float* wx = cell ? wx2 : wx1;
    const float* wh = cell ? wh2 : wh1;
    const float* bx = cell ? bx2 : bx1;
    const float* bh = cell ? bh2 : bh1;

    int w    = tid >> 6;              // wave id = unit subtile (units 16w..16w+15)
    int l    = tid & 63;
    int quad = l >> 4;
    int c16  = l & 15;

    __shared__ float xl[MT * 514];                        // [seq][t*2+c], pad 514
    __shared__ __align__(16) __bf16 hb[2][2][MT][72];     // [buf][hi/lo][seq][u pad72]

    // ---- stage x for this block's 16 sequences (all 256 steps) ----
    {
        int seq0 = tile * MT;
        for (int i = 0; i < 32; ++i) {
            int idx = tid + 256 * i;          // m*512 + t*2 + c
            int m = idx >> 9;
            int tc = idx & 511;
            int t = tc >> 1, c = tc & 1;
            int seq = seq0 + m;
            int b = seq / PIX, p = seq % PIX;
            xl[m * 514 + tc] = x[((b * T_STEPS + t) * 2 + c) * PIX + p];
        }
    }
    // ---- zero h buffers ----
    {
        __bf16* hz = &hb[0][0][0][0];
        for (int i = tid; i < 2 * 2 * MT * 72; i += 256) hz[i] = (__bf16)0.0f;
    }

    // ---- W as A-operand fragments (hi+lo), per gate & K-slab, PRESCALED ----
    bf16x8 Whi[4][2], Wlo[4][2];
    float btot[4][4], wxa[4][4], wxb[4][4];
#pragma unroll
    for (int g = 0; g < 4; ++g) {
        float sg = (g == 3) ? (-2.0f * LOG2E) : (-LOG2E);
        int col = 64 * g + 16 * w + c16;
#pragma unroll
        for (int r = 0; r < 4; ++r) {
            int u = 64 * g + 16 * w + 4 * quad + r;   // this thread's C-row units
            btot[g][r] = sg * (bx[u] + bh[u]);
            wxa[g][r]  = sg * wx[u];
            wxb[g][r]  = sg * wx[256 + u];
        }
#pragma unroll
        for (int q = 0; q < 2; ++q) {
#pragma unroll
            for (int j = 0; j < 8; ++j) {
                int k = 32 * q + 8 * quad + j;
                float wv = sg * wh[k * 256 + col];
                __bf16 hi = (__bf16)wv;
                Whi[g][q][j] = hi;
                Wlo[g][q][j] = (__bf16)(wv - (float)hi);
            }
        }
    }

    float cst[4]  = {0.f, 0.f, 0.f, 0.f};
    float hfin[4] = {0.f, 0.f, 0.f, 0.f};

    __syncthreads();
    float2 xv = *(const float2*)&xl[c16 * 514 + (cell ? (T_STEPS - 1) : 0) * 2];

#pragma unroll 2
    for (int t = 0; t < T_STEPS; ++t) {
        int rb = t & 1, wb = rb ^ 1;

        bf16x8 Bh[2], Bl[2];
#pragma unroll
        for (int q = 0; q < 2; ++q) {
            Bh[q] = *(const bf16x8*)&hb[rb][0][c16][32 * q + 8 * quad];
            Bl[q] = *(const bf16x8*)&hb[rb][1][c16][32 * q + 8 * quad];
        }

        f32x4 acc[4];
#pragma unroll
        for (int g = 0; g < 4; ++g) {
#pragma unroll
            for (int r = 0; r < 4; ++r)
                acc[g][r] = fmaf(xv.y, wxb[g][r], fmaf(xv.x, wxa[g][r], btot[g][r]));
        }
        // product-major: 6 rounds x 4 gates -> 4-way dependent-chain ILP.
#pragma unroll
        for (int g = 0; g < 4; ++g)
            acc[g] = __builtin_amdgcn_mfma_f32_16x16x32_bf16(Whi[g][0], Bh[0], acc[g], 0, 0, 0);
#pragma unroll
        for (int g = 0; g < 4; ++g)
            acc[g] = __builtin_amdgcn_mfma_f32_16x16x32_bf16(Whi[g][1], Bh[1], acc[g], 0, 0, 0);
#pragma unroll
        for (int g = 0; g < 4; ++g)
            acc[g] = __builtin_amdgcn_mfma_f32_16x16x32_bf16(Wlo[g][0], Bh[0], acc[g], 0, 0, 0);
#pragma unroll
        for (int g = 0; g < 4; ++g)
            acc[g] = __builtin_amdgcn_mfma_f32_16x16x32_bf16(Wlo[g][1], Bh[1], acc[g], 0, 0, 0);
#pragma unroll
        for (int g = 0; g < 4; ++g)
            acc[g] = __builtin_amdgcn_mfma_f32_16x16x32_bf16(Whi[g][0], Bl[0], acc[g], 0, 0, 0);
#pragma unroll
        for (int g = 0; g < 4; ++g)
            acc[g] = __builtin_amdgcn_mfma_f32_16x16x32_bf16(Whi[g][1], Bl[1], acc[g], 0, 0, 0);

        // exp phase: 16 independent transcendentals (acc IS the exp2 arg)
        float ei[4], ef[4], eo[4], eg[4];
#pragma unroll
        for (int r = 0; r < 4; ++r) {
            ei[r] = __builtin_amdgcn_exp2f(acc[0][r]);
            ef[r] = __builtin_amdgcn_exp2f(acc[1][r]);
            eo[r] = __builtin_amdgcn_exp2f(acc[2][r]);
            eg[r] = __builtin_amdgcn_exp2f(acc[3][r]);
        }

        bf16x4 ph, pl;
#pragma unroll
        for (int r = 0; r < 4; ++r) {
            float sf  = __builtin_amdgcn_rcpf(1.0f + ef[r]);
            float itg = (1.0f - eg[r]) * __builtin_amdgcn_rcpf((1.0f + ei[r]) * (1.0f + eg[r]));
            float c   = fmaf(sf, cst[r], itg);
            cst[r] = c;
            float ec = __builtin_amdgcn_exp2f(-2.0f * LOG2E * c);
            float h  = (1.0f - ec) * __builtin_amdgcn_rcpf((1.0f + eo[r]) * (1.0f + ec));
            hfin[r] = h;
            __bf16 hi = (__bf16)h;
            ph[r] = hi;
            pl[r] = (__bf16)(h - (float)hi);
        }
        *(bf16x4*)&hb[wb][0][c16][16 * w + 4 * quad] = ph;
        *(bf16x4*)&hb[wb][1][c16][16 * w + 4 * quad] = pl;

        {
            int txn = (cell ? (T_STEPS - 2 - t) : (t + 1)) & 255;
            xv = *(const float2*)&xl[c16 * 514 + txn * 2];
        }
        __syncthreads();
    }

    {
        int seq = tile * MT + c16;
        int b = seq / PIX, p = seq % PIX;
#pragma unroll
        for (int r = 0; r < 4; ++r) {
            int u = 16 * w + 4 * quad + r;
            feat[(size_t)(sub * 32 + b) * 7040 + (cell * 64 + u) * PIX + p] = hfin[r];
        }
    }
}

// ---------------------------------------------------------------------------
// FC slim (R10 inner loop, proven): out[64][N] += A[64][kchunk] @ W[kchunk][N].
// Block = 64 m x 64 n. Lane owns ONE n (acc[16] = 16 VGPR). Wave w -> rows
// 16w..16w+15 (broadcast b128 A reads). kcur==128 path: 8x16 static groups.
// Accumulation into bias-pre-initialized out via native f32 atomics.
// ---------------------------------------------------------------------------
__global__ __launch_bounds__(256) void fc_gemm(const float* __restrict__ A,
                                               const float* __restrict__ W,
                                               float* __restrict__ out,
                                               int K, int N, int kchunk) {
    __shared__ __align__(16) float al[FC_SUB * 68];   // [kc][m pad68]
    int tid = threadIdx.x;
    int l   = tid & 63;
    int wv  = tid >> 6;
    int k0   = blockIdx.y * kchunk;
    int kend = min(K, k0 + kchunk);

    int n  = blockIdx.x * 64 + l;
    int ne = min(n, N - 1);                // clamped load index (stores guarded)

    float acc[16];
#pragma unroll
    for (int i = 0; i < 16; ++i) acc[i] = 0.0f;

    for (int ks = k0; ks < kend; ks += FC_SUB) {
        int kcur = min(FC_SUB, kend - ks);
        __syncthreads();                   // protect al reuse
        // ---- stage A[0:64][ks:ks+kcur]: 32 independent coalesced loads ----
        if (kcur == FC_SUB) {
#pragma unroll
            for (int i = 0; i < 32; ++i) {
                int idx = tid + 256 * i;       // m = idx>>7, kc = idx&127
                int m = idx >> 7, kc = idx & 127;
                al[kc * 68 + m] = A[(size_t)m * K + ks + kc];
            }
        } else {
#pragma unroll
            for (int i = 0; i < 32; ++i) {
                int idx = tid + 256 * i;
                int m = idx >> 7, kc = idx & 127;
                if (kc < kcur) al[kc * 68 + m] = A[(size_t)m * K + ks + kc];
            }
        }
        __syncthreads();

        const float* wr = W + (size_t)ks * N + ne;
        if (kcur == FC_SUB) {
            // hot path: 8 static groups of 16, fully unrolled
#pragma unroll
            for (int g8 = 0; g8 < FC_SUB / FC_GRP; ++g8) {
                float wbuf[FC_GRP];
#pragma unroll
                for (int j = 0; j < FC_GRP; ++j)
                    wbuf[j] = wr[(size_t)(g8 * FC_GRP + j) * N];
#pragma unroll
                for (int j = 0; j < FC_GRP; ++j) {
                    const float4* ap = (const float4*)&al[(g8 * FC_GRP + j) * 68 + 16 * wv];
#pragma unroll
                    for (int i = 0; i < 4; ++i) {
                        float4 a = ap[i];
                        acc[4 * i + 0] = fmaf(a.x, wbuf[j], acc[4 * i + 0]);
                        acc[4 * i + 1] = fmaf(a.y, wbuf[j], acc[4 * i + 1]);
                        acc[4 * i + 2] = fmaf(a.z, wbuf[j], acc[4 * i + 2]);
                        acc[4 * i + 3] = fmaf(a.w, wbuf[j], acc[4 * i + 3]);
                    }
                }
            }
        } else {
            int kc0 = 0;
            for (; kc0 + FC_GRP <= kcur; kc0 += FC_GRP) {
                float wbuf[FC_GRP];
#pragma unroll
                for (int j = 0; j < FC_GRP; ++j)
                    wbuf[j] = wr[(size_t)(kc0 + j) * N];
#pragma unroll
                for (int j = 0; j < FC_GRP; ++j) {
                    const float4* ap = (const float4*)&al[(kc0 + j) * 68 + 16 * wv];
#pragma unroll
                    for (int i = 0; i < 4; ++i) {
                        float4 a = ap[i];
                        acc[4 * i + 0] = fmaf(a.x, wbuf[j], acc[4 * i + 0]);
                        acc[4 * i + 1] = fmaf(a.y, wbuf[j], acc[4 * i + 1]);
                        acc[4 * i + 2] = fmaf(a.z, wbuf[j], acc[4 * i + 2]);
                        acc[4 * i + 3] = fmaf(a.w, wbuf[j], acc[4 * i + 3]);
                    }
                }
            }
            for (; kc0 < kcur; ++kc0) {
                float wvv = wr[(size_t)kc0 * N];
                const float4* ap = (const float4*)&al[kc0 * 68 + 16 * wv];
#pragma unroll
                for (int i = 0; i < 4; ++i) {
                    float4 a = ap[i];
                    acc[4 * i + 0] = fmaf(a.x, wvv, acc[4 * i + 0]);
                    acc[4 * i + 1] = fmaf(a.y, wvv, acc[4 * i + 1]);
                    acc[4 * i + 2] = fmaf(a.z, wvv, acc[4 * i + 2]);
                    acc[4 * i + 3] = fmaf(a.w, wvv, acc[4 * i + 3]);
                }
            }
        }
    }

    if (n < N) {
        float* pr = out + n;
#pragma unroll
        for (int i = 0; i < 16; ++i)
            unsafeAtomicAdd(&pr[(size_t)(16 * wv + i) * N], acc[i]);
    }
}

extern "C" void kernel_launch(void* const* d_in, const int* in_sizes, int n_in,
                              void* d_out, int out_size, void* d_ws, size_t ws_size,
                              hipStream_t stream) {
    const float* x1  = (const float*)d_in[0];
    const float* x2  = (const float*)d_in[1];
    const float* wx1 = (const float*)d_in[2];
    const float* wh1 = (const float*)d_in[3];
    const float* bx1 = (const float*)d_in[4];
    const float* bh1 = (const float*)d_in[5];
    const float* wx2 = (const float*)d_in[6];
    const float* wh2 = (const float*)d_in[7];
    const float* bx2 = (const float*)d_in[8];
    const float* bh2 = (const float*)d_in[9];
    const float* fw2 = (const float*)d_in[10];
    const float* fb2 = (const float*)d_in[11];
    const float* fw3 = (const float*)d_in[12];
    const float* fb3 = (const float*)d_in[13];
    const float* fw4 = (const float*)d_in[14];
    const float* fb4 = (const float*)d_in[15];
    const float* fw5 = (const float*)d_in[16];
    const float* fb5 = (const float*)d_in[17];

    char* ws = (char*)d_ws;
    float* feat = (float*)ws;                                   // [64][7040]
    float* t1   = feat + (size_t)64 * 7040;                     // [64][3400]
    float* t2   = t1   + (size_t)64 * 3400;                     // [64][1000]
    float* t3   = t2   + (size_t)64 * 1000;                     // [64][500]
    float* o    = (float*)d_out;                                // [64][50]

    // lstm (440 blocks) + bias prefill (10 blocks) in one launch
    lstm_kernel<<<dim3(LSTM_BLOCKS + INIT_BLOCKS), dim3(256), 0, stream>>>(
        x1, x2, wx1, wh1, bx1, bh1, wx2, wh2, bx2, bh2, feat,
        fb2, fb3, fb4, fb5, t1, t2, t3, o);

    // atomic split-K GEMMs (out pre-filled with bias)
    // fc2: 54 n-tiles x 19 k-splits, kchunk 384 (= 3 full 128-stages; last
    // split is exactly 128) -> 1026 blocks ~ one fully-packed round at 4/CU.
    fc_gemm<<<dim3(54, 19), dim3(256), 0, stream>>>(feat, fw2, t1, 7040, 3400, 384);
    fc_gemm<<<dim3(16, 54), dim3(256), 0, stream>>>(t1, fw3, t2, 3400, 1000, 64);
    fc_gemm<<<dim3(8, 16), dim3(256), 0, stream>>>(t2, fw4, t3, 1000, 500, 64);
    fc_gemm<<<dim3(1, 16), dim3(256), 0, stream>>>(t3, fw5, o, 500, 50, 32);
}